// Round 6
// baseline (43.653 us; speedup 1.0000x reference)
//
#include <hip/hip_runtime.h>
#include <math.h>
#include <stdint.h>

#define NHEAD 4
#define DD 100
#define NW 39            // word rows
#define BLOCK 256

typedef __attribute__((address_space(3))) uint32_t lds_t;
typedef const __attribute__((address_space(1))) uint32_t glb_t;

__global__ __launch_bounds__(BLOCK, 8) void ts_enc(
    const float* __restrict__ x,       // [4800][40][100]
    const float* __restrict__ w_att,   // [4][100]
    const float* __restrict__ b_att,   // [4][100]
    float* __restrict__ out)           // [4800][400]
{
    __shared__ float tile[40 * DD];      // 16 KB (words rows used by Phase A scatter)
    __shared__ float scp[4][NHEAD][40];  // [wave-partial][head][n]

    const int tid  = threadIdx.x;
    const int wv   = __builtin_amdgcn_readfirstlane(tid >> 6);
    const int lane = tid & 63;
    const float* xsite = x + (size_t)blockIdx.x * (40 * DD);

    // ---- stage site tile: async global->LDS, 16 B/lane ----
    #pragma unroll
    for (int i = 0; i < 4; ++i) {
        const int cf = i * BLOCK + tid;
        if (cf < 1000) {
            glb_t* g = (glb_t*)(xsite + cf * 4);
            lds_t* l = (lds_t*)(tile + (i * BLOCK + wv * 64) * 4);
            __builtin_amdgcn_global_load_lds(g, l, 16, 0, 0);
        }
    }
    __syncthreads();

    // ---- Phase A: scores; d-chunks split across waves, lane = n, all 4 heads ----
    // te*leaky(p) == (0.65*te)*p + (0.35*te)*|p|.
    // te4 / w4 / b4: wave-uniform global addresses -> scalar loads (K$/SMEM pipe).
    // words: the only DS reads left in Phase A.
    const bool act  = lane < NW;
    const int  nrow = act ? lane : NW - 1;
    const float* wrow = tile + (1 + nrow) * DD;
    float acc[NHEAD] = {0.f, 0.f, 0.f, 0.f};

    for (int c = wv; c < 25; c += 4) {
        const float4 te4 = *(const float4*)(xsite + c * 4);      // s_load (uniform)
        const float4 v4  = *(const float4*)(wrow + c * 4);       // ds_read_b128
        const float a65x = 0.65f * te4.x, a35x = 0.35f * te4.x;
        const float a65y = 0.65f * te4.y, a35y = 0.35f * te4.y;
        const float a65z = 0.65f * te4.z, a35z = 0.35f * te4.z;
        const float a65w = 0.65f * te4.w, a35w = 0.35f * te4.w;
        #pragma unroll
        for (int h = 0; h < NHEAD; ++h) {
            const float4 w4 = *(const float4*)(w_att + h * DD + c * 4);
            const float4 b4 = *(const float4*)(b_att + h * DD + c * 4);
            float p0 = fmaf(v4.x, w4.x, b4.x);
            float p1 = fmaf(v4.y, w4.y, b4.y);
            float p2 = fmaf(v4.z, w4.z, b4.z);
            float p3 = fmaf(v4.w, w4.w, b4.w);
            float t  = fmaf(a65x, p0, fmaf(a35x, fabsf(p0), acc[h]));
            t        = fmaf(a65y, p1, fmaf(a35y, fabsf(p1), t));
            t        = fmaf(a65z, p2, fmaf(a35z, fabsf(p2), t));
            acc[h]   = fmaf(a65w, p3, fmaf(a35w, fabsf(p3), t));
        }
    }
    if (act) {
        scp[wv][0][lane] = acc[0];
        scp[wv][1][lane] = acc[1];
        scp[wv][2][lane] = acc[2];
        scp[wv][3][lane] = acc[3];
    }
    __syncthreads();

    // ---- Phase B: softmax in-wave (wave wv = head wv, lane = n) ----
    float sc = -INFINITY;
    if (act) sc = (scp[0][wv][lane] + scp[1][wv][lane])
                + (scp[2][wv][lane] + scp[3][wv][lane]);
    float mx = sc;
    #pragma unroll
    for (int off = 32; off; off >>= 1) mx = fmaxf(mx, __shfl_xor(mx, off));
    float p = act ? __expf(sc - mx) : 0.f;
    float sm = p;
    #pragma unroll
    for (int off = 32; off; off >>= 1) sm += __shfl_xor(sm, off);
    const float a = p / sm;          // lane n holds att[head=wv][n]

    // ---- Phase C: wave wv = head wv; 50 lanes x float2; words from GLOBAL (L2-hot);
    //      att scalars via v_readlane (VALU), zero DS traffic, no barrier ----
    const int l2 = lane < 50 ? lane : 49;     // clamp idle lanes in-bounds
    const float* wbase = xsite + DD + l2 * 2; // row n=0, this lane's float2
    float2 ca = make_float2(0.f, 0.f);
    #pragma unroll
    for (int n = 0; n < NW; ++n) {
        const int   ai   = __builtin_amdgcn_readlane(__builtin_bit_cast(int, a), n);
        const float attn = __builtin_bit_cast(float, ai);        // SGPR scalar
        const float2 wd  = *(const float2*)(wbase + n * DD);     // coalesced 400B row
        ca.x = fmaf(attn, wd.x, ca.x);
        ca.y = fmaf(attn, wd.y, ca.y);
    }
    if (lane < 50)
        *(float2*)(out + (size_t)blockIdx.x * (NHEAD * DD) + wv * DD + lane * 2) = ca;
}

extern "C" void kernel_launch(void* const* d_in, const int* in_sizes, int n_in,
                              void* d_out, int out_size, void* d_ws, size_t ws_size,
                              hipStream_t stream) {
    const float* x     = (const float*)d_in[0];
    const float* w_att = (const float*)d_in[1];
    const float* b_att = (const float*)d_in[2];
    float* out = (float*)d_out;

    const int sites = 8 * 30 * 20;   // 4800
    ts_enc<<<sites, BLOCK, 0, stream>>>(x, w_att, b_att, out);
}

// Round 7
// 29.443 us; speedup vs baseline: 1.4826x; 1.4826x over previous
//
#include <hip/hip_runtime.h>
#include <math.h>
#include <stdint.h>

#define NHEAD 4
#define DD 100
#define NW 39            // word rows
#define BLOCK 256

typedef __attribute__((address_space(3))) uint32_t lds_t;
typedef const __attribute__((address_space(1))) uint32_t glb_t;

__global__ __launch_bounds__(BLOCK, 8) void ts_enc(
    const float* __restrict__ x,       // [4800][40][100]
    const float* __restrict__ w_att,   // [4][100]
    const float* __restrict__ b_att,   // [4][100]
    float* __restrict__ out)           // [4800][400]
{
    __shared__ float tile[40 * DD];      // 16000 B: row0 = type_emb, rows 1..39 = words
    __shared__ float shbuf[800];         // union: scp[4][4][40] (640 fl) / P[2][4][100] (800 fl)
    __shared__ float att_T[40][NHEAD];   // [n][head]

    float (*scp)[NHEAD][40] = (float (*)[NHEAD][40])shbuf;  // [wave][head][n]
    float (*P)[NHEAD][DD]   = (float (*)[NHEAD][DD])shbuf;  // [wavepair][head][d]

    const int tid  = threadIdx.x;
    const int wv   = __builtin_amdgcn_readfirstlane(tid >> 6);
    const int lane = tid & 63;
    const float* xsite = x + (size_t)blockIdx.x * (40 * DD);

    // ---- stage site tile: async global->LDS, 16 B/lane ----
    #pragma unroll
    for (int i = 0; i < 4; ++i) {
        const int cf = i * BLOCK + tid;
        if (cf < 1000) {
            glb_t* g = (glb_t*)(xsite + cf * 4);
            lds_t* l = (lds_t*)(tile + (i * BLOCK + wv * 64) * 4);
            __builtin_amdgcn_global_load_lds(g, l, 16, 0, 0);
        }
    }
    __syncthreads();                                   // barrier 1 (drains vmcnt)

    // ---- Phase A: scores; d-chunks split across waves, lane = n, all 4 heads ----
    // te*leaky(p) == (0.65*te)*p + (0.35*te)*|p|; te4/w4/b4 wave-uniform -> scalar pipe.
    const bool act  = lane < NW;
    const int  nrow = act ? lane : NW - 1;             // clamped lanes merge (broadcast)
    const float* wrow = tile + (1 + nrow) * DD;
    float acc[NHEAD] = {0.f, 0.f, 0.f, 0.f};

    for (int c = wv; c < 25; c += 4) {
        const float4 te4 = *(const float4*)(xsite + c * 4);    // uniform global (K$)
        const float4 v4  = *(const float4*)(wrow + c * 4);     // the only DS read in A
        const float a65x = 0.65f * te4.x, a35x = 0.35f * te4.x;
        const float a65y = 0.65f * te4.y, a35y = 0.35f * te4.y;
        const float a65z = 0.65f * te4.z, a35z = 0.35f * te4.z;
        const float a65w = 0.65f * te4.w, a35w = 0.35f * te4.w;
        #pragma unroll
        for (int h = 0; h < NHEAD; ++h) {
            const float4 w4 = *(const float4*)(w_att + h * DD + c * 4);
            const float4 b4 = *(const float4*)(b_att + h * DD + c * 4);
            float p0 = fmaf(v4.x, w4.x, b4.x);
            float p1 = fmaf(v4.y, w4.y, b4.y);
            float p2 = fmaf(v4.z, w4.z, b4.z);
            float p3 = fmaf(v4.w, w4.w, b4.w);
            float t  = fmaf(a65x, p0, fmaf(a35x, fabsf(p0), acc[h]));
            t        = fmaf(a65y, p1, fmaf(a35y, fabsf(p1), t));
            t        = fmaf(a65z, p2, fmaf(a35z, fabsf(p2), t));
            acc[h]   = fmaf(a65w, p3, fmaf(a35w, fabsf(p3), t));
        }
    }
    if (act) {
        scp[wv][0][lane] = acc[0];
        scp[wv][1][lane] = acc[1];
        scp[wv][2][lane] = acc[2];
        scp[wv][3][lane] = acc[3];
    }
    __syncthreads();                                   // barrier 2

    // ---- Phase B: softmax in-wave (wave wv = head wv, lane = n) ----
    float sc = -INFINITY;
    if (act) sc = (scp[0][wv][lane] + scp[1][wv][lane])
                + (scp[2][wv][lane] + scp[3][wv][lane]);
    float mx = sc;
    #pragma unroll
    for (int off = 32; off; off >>= 1) mx = fmaxf(mx, __shfl_xor(mx, off));
    float p = act ? __expf(sc - mx) : 0.f;
    float sm = p;
    #pragma unroll
    for (int off = 32; off; off >>= 1) sm += __shfl_xor(sm, off);
    if (act) att_T[lane][wv] = p / sm;                 // [n][head]
    __syncthreads();                                   // barrier 3 (att_T ready; scp dead)

    // ---- Phase C: waves 0,1 split n (even/odd); lane = float2 d-chunk (50 active);
    //      acc for all 4 heads in regs; one b64 words read + one b128 att bcast per n ----
    if (wv < 2) {
        const int l2 = lane < 50 ? lane : 49;          // clamp idle lanes
        const float* wbase = tile + DD + l2 * 2;
        float2 a0 = {0,0}, a1 = {0,0}, a2 = {0,0}, a3 = {0,0};
        for (int n = wv; n < NW; n += 2) {
            const float4 at = *(const float4*)&att_T[n][0];      // broadcast (same addr)
            const float2 wd = *(const float2*)(wbase + n * DD);  // 50-lane b64, 2-way banks
            a0.x = fmaf(at.x, wd.x, a0.x); a0.y = fmaf(at.x, wd.y, a0.y);
            a1.x = fmaf(at.y, wd.x, a1.x); a1.y = fmaf(at.y, wd.y, a1.y);
            a2.x = fmaf(at.z, wd.x, a2.x); a2.y = fmaf(at.z, wd.y, a2.y);
            a3.x = fmaf(at.w, wd.x, a3.x); a3.y = fmaf(at.w, wd.y, a3.y);
        }
        if (lane < 50) {
            *(float2*)&P[wv][0][lane * 2] = a0;
            *(float2*)&P[wv][1][lane * 2] = a1;
            *(float2*)&P[wv][2][lane * 2] = a2;
            *(float2*)&P[wv][3][lane * 2] = a3;
        }
    }
    __syncthreads();                                   // barrier 4 (P ready)

    // ---- combine the two n-partials and store (threads 0..99, one float4 each) ----
    if (tid < 100) {
        const int h  = tid / 25;
        const int c4 = tid - h * 25;
        const float4 q0 = *(const float4*)&P[0][h][c4 * 4];
        const float4 q1 = *(const float4*)&P[1][h][c4 * 4];
        float4 r;
        r.x = q0.x + q1.x;
        r.y = q0.y + q1.y;
        r.z = q0.z + q1.z;
        r.w = q0.w + q1.w;
        *(float4*)(out + (size_t)blockIdx.x * (NHEAD * DD) + h * DD + c4 * 4) = r;
    }
}

extern "C" void kernel_launch(void* const* d_in, const int* in_sizes, int n_in,
                              void* d_out, int out_size, void* d_ws, size_t ws_size,
                              hipStream_t stream) {
    const float* x     = (const float*)d_in[0];
    const float* w_att = (const float*)d_in[1];
    const float* b_att = (const float*)d_in[2];
    float* out = (float*)d_out;

    const int sites = 8 * 30 * 20;   // 4800
    ts_enc<<<sites, BLOCK, 0, stream>>>(x, w_att, b_att, out);
}